// Round 1
// baseline (1387.204 us; speedup 1.0000x reference)
//
#include <hip/hip_runtime.h>
#include <hip/hip_bf16.h>

// LiftedConv: X (8,16,8,128,128) f32, weights (16,200,16) f32
// out (8,16,8,128,128) f32  ==  conv2d(X.reshape(8,128,128,128),
//   Kst (128,128,5,5), pad=2) with Kst built from B-spline basis.
//
// Stage 1: build Kst[tap=i*5+j][icT=c*8+ns][ocT=n*16+o]  (fp32, in d_ws)
// Stage 2: direct fp32 conv, one block per (b, y) row, 128 oc x 128 x.

#define TWO_PI_D 6.283185307179586
#define PI_D     3.141592653589793
#define STEP_D   0.7853981633974483   // 2*pi/8

__device__ __forceinline__ double b2_spline(double x) {
    auto sgn = [](double v) -> double { return (v > 0.0) ? 1.0 : ((v < 0.0) ? -1.0 : 0.0); };
    double t1 = -3.0 * (x - 0.5) * (x - 0.5) * sgn(0.5 - x);
    double t2 = (x - 1.5) * (x - 1.5) * sgn(1.5 - x);
    double t3 = -3.0 * (1.0 + 2.0 * x) * (1.0 + 2.0 * x) * sgn(0.5 + x) * 0.25;
    double t4 = (3.0 + 2.0 * x) * (3.0 + 2.0 * x) * sgn(1.5 + x) * 0.25;
    return (t1 + t2 + t3 + t4) * 0.25;
}

__device__ __forceinline__ double pmod2pi(double a) {
    double r = fmod(a, TWO_PI_D);
    if (r < 0.0) r += TWO_PI_D;
    return r;
}

// grid (25, 8, 8) = (tap, n_samp, n); block 256 = (c=t>>4, o=t&15)
__global__ __launch_bounds__(256) void build_kst(const float* __restrict__ W,
                                                 float* __restrict__ Kst) {
    __shared__ float coeff[200];
    const int tap = blockIdx.x;
    const int i = tap / 5, j = tap % 5;
    const int ns = blockIdx.y;   // n_samp (input rotation channel)
    const int n  = blockIdx.z;   // output rotation
    const int t = threadIdx.x;

    if (t < 200) {
        const int p = t >> 3, bb = t & 7;
        const int pi_ = p / 5, pj = p % 5;
        const double h = n * STEP_D;
        const double ch = cos(h), sh = sin(h);
        const double gi = (double)(i - 2), gj = (double)(j - 2);
        // R(-h) @ grid:  xxs0 = cos(h)*gi + sin(h)*gj ; xxs1 = -sin(h)*gi + cos(h)*gj
        const double xxs0 = ch * gi + sh * gj;
        const double xxs1 = -sh * gi + ch * gj;
        const double sx = b2_spline((double)(pi_ - 2) - xxs0) *
                          b2_spline((double)(pj - 2) - xxs1);
        const double hs = pmod2pi(ns * STEP_D - h);
        const double hd = fabs(pmod2pi(hs - bb * STEP_D + PI_D) - PI_D);
        const double shv = b2_spline(hd / STEP_D);
        coeff[t] = (float)(sx * shv);
    }
    __syncthreads();

    const int c = t >> 4, o = t & 15;
    const float* wc = W + (size_t)c * 3200 + o;  // W[c][m][o], m-stride 16
    float acc = 0.f;
    for (int m = 0; m < 200; ++m) {
        float cm = coeff[m];
        if (cm != 0.f) acc = fmaf(cm, wc[m * 16], acc);  // block-uniform branch
    }
    Kst[((size_t)tap * 128 + (c * 8 + ns)) * 128 + (n * 16 + o)] = acc;
}

// grid (128, 8) = (y, b); block 256.
// Each thread: 8 oc (oc0=(t>>4)*8) x 8 x (x0=(t&15)*8) register tile.
__global__ __launch_bounds__(256, 3) void lifted_conv(const float* __restrict__ X,
                                                      const float* __restrict__ Kst,
                                                      float* __restrict__ out) {
    __shared__ float A_lds[16][132];        // [ic][x+2] one input row chunk w/ halo
    __shared__ float W_lds[5][16][128];     // [dx][ic][oc]
    const int t = threadIdx.x;
    const int y = blockIdx.x, b = blockIdx.y;
    const int oc0 = (t >> 4) * 8;
    const int x0 = (t & 15) * 8;

    float acc[8][8];
#pragma unroll
    for (int a = 0; a < 8; ++a)
#pragma unroll
        for (int q = 0; q < 8; ++q) acc[a][q] = 0.f;

    const float4* K4 = (const float4*)Kst;

    for (int dy = 0; dy < 5; ++dy) {
        const int yy = y + dy - 2;
        const bool rowok = (yy >= 0) && (yy < 128);
        for (int icc = 0; icc < 8; ++icc) {
            __syncthreads();
            // stage A: 16 ic x 132 cols (zero-padded halo)
#pragma unroll
            for (int it = 0; it < 9; ++it) {
                int idx = t + it * 256;
                if (idx < 2112) {
                    int ic = idx / 132;
                    int cx = idx - ic * 132;
                    int xx = cx - 2;
                    float v = 0.f;
                    if (rowok && xx >= 0 && xx < 128)
                        v = X[(((size_t)b * 128 + (icc * 16 + ic)) * 128 + yy) * 128 + xx];
                    A_lds[ic][cx] = v;
                }
            }
            // stage W: 5 dx x 16 ic x 128 oc  (2560 float4, 10 per thread)
#pragma unroll
            for (int it = 0; it < 10; ++it) {
                int cidx = t + it * 256;
                int dx = cidx >> 9;
                int rem = cidx & 511;
                int ic = rem >> 5;
                int oq = rem & 31;
                float4 v = K4[((size_t)(dy * 5 + dx) * 128 + (icc * 16 + ic)) * 32 + oq];
                *(float4*)&W_lds[dx][ic][oq * 4] = v;
            }
            __syncthreads();
            // compute: per ic, 12 a-values cover all 5 dx shifts for 8 x outputs
#pragma unroll 1
            for (int ic = 0; ic < 16; ++ic) {
                float a12[12];
                *(float4*)&a12[0] = *(const float4*)&A_lds[ic][x0];
                *(float4*)&a12[4] = *(const float4*)&A_lds[ic][x0 + 4];
                *(float4*)&a12[8] = *(const float4*)&A_lds[ic][x0 + 8];
                float w[5][8];
#pragma unroll
                for (int dx = 0; dx < 5; ++dx) {
                    *(float4*)&w[dx][0] = *(const float4*)&W_lds[dx][ic][oc0];
                    *(float4*)&w[dx][4] = *(const float4*)&W_lds[dx][ic][oc0 + 4];
                }
#pragma unroll
                for (int dx = 0; dx < 5; ++dx)
#pragma unroll
                    for (int oo = 0; oo < 8; ++oo)
#pragma unroll
                        for (int ox = 0; ox < 8; ++ox)
                            acc[oo][ox] = fmaf(w[dx][oo], a12[ox + dx], acc[oo][ox]);
            }
        }
    }
    // out[b][o][n][y][x], ocT = n*16 + o
#pragma unroll
    for (int oo = 0; oo < 8; ++oo) {
        int ocT = oc0 + oo;
        int n = ocT >> 4, o = ocT & 15;
        size_t base = ((((size_t)b * 16 + o) * 8 + n) * (size_t)128 + y) * 128 + x0;
        float4 v0 = make_float4(acc[oo][0], acc[oo][1], acc[oo][2], acc[oo][3]);
        float4 v1 = make_float4(acc[oo][4], acc[oo][5], acc[oo][6], acc[oo][7]);
        *(float4*)&out[base] = v0;
        *(float4*)&out[base + 4] = v1;
    }
}

extern "C" void kernel_launch(void* const* d_in, const int* in_sizes, int n_in,
                              void* d_out, int out_size, void* d_ws, size_t ws_size,
                              hipStream_t stream) {
    const float* X = (const float*)d_in[0];
    const float* W = (const float*)d_in[1];
    float* out = (float*)d_out;
    float* Kst = (float*)d_ws;  // 25*128*128 f32 = 1.6 MB

    build_kst<<<dim3(25, 8, 8), 256, 0, stream>>>(W, Kst);
    lifted_conv<<<dim3(128, 8), 256, 0, stream>>>(X, Kst, out);
}

// Round 3
// 330.005 us; speedup vs baseline: 4.2036x; 4.2036x over previous
//
#include <hip/hip_runtime.h>
#include <hip/hip_bf16.h>

// LiftedConv via bf16 MFMA implicit GEMM.
// Stage 1 (build_kst): B-spline basis x weights -> Af in MFMA A-fragment order:
//   Af[tap(25)][kc(4)][mf(8)][lane(64)][8] bf16  (ocT = frag row, ic = k dim)
// Stage 2 (lifted_conv_mfma): per (b,y) block computes 128 ocT x 128 x via
//   16x16x32 bf16 MFMA; X row staged in LDS ic-contiguous with XOR swizzle.

#define TWO_PI_D 6.283185307179586
#define PI_D     3.141592653589793
#define STEP_D   0.7853981633974483   // 2*pi/8

typedef __attribute__((ext_vector_type(8))) short short8v;
typedef __attribute__((ext_vector_type(4))) float f32x4;

__device__ __forceinline__ double b2_spline(double x) {
    auto sgn = [](double v) -> double { return (v > 0.0) ? 1.0 : ((v < 0.0) ? -1.0 : 0.0); };
    double t1 = -3.0 * (x - 0.5) * (x - 0.5) * sgn(0.5 - x);
    double t2 = (x - 1.5) * (x - 1.5) * sgn(1.5 - x);
    double t3 = -3.0 * (1.0 + 2.0 * x) * (1.0 + 2.0 * x) * sgn(0.5 + x) * 0.25;
    double t4 = (3.0 + 2.0 * x) * (3.0 + 2.0 * x) * sgn(1.5 + x) * 0.25;
    return (t1 + t2 + t3 + t4) * 0.25;
}

__device__ __forceinline__ double pmod2pi(double a) {
    double r = fmod(a, TWO_PI_D);
    if (r < 0.0) r += TWO_PI_D;
    return r;
}

__device__ __forceinline__ ushort f2bf(float f) {
    union { float f; uint u; } v; v.f = f;
    uint u = v.u;
    return (ushort)((u + 0x7FFFu + ((u >> 16) & 1u)) >> 16);  // RNE
}

// grid (25, 8, 8) = (tap, n_samp, n); block 256 = (c=t>>4, o=t&15)
__global__ __launch_bounds__(256) void build_kst(const float* __restrict__ W,
                                                 ushort* __restrict__ Af) {
    __shared__ float coeff[200];
    const int tap = blockIdx.x;
    const int i = tap / 5, j = tap % 5;
    const int ns = blockIdx.y;   // input rotation channel
    const int n  = blockIdx.z;   // output rotation
    const int t = threadIdx.x;

    if (t < 200) {
        const int p = t >> 3, bb = t & 7;
        const int pi_ = p / 5, pj = p % 5;
        const double h = n * STEP_D;
        const double ch = cos(h), sh = sin(h);
        const double gi = (double)(i - 2), gj = (double)(j - 2);
        const double xxs0 = ch * gi + sh * gj;
        const double xxs1 = -sh * gi + ch * gj;
        const double sx = b2_spline((double)(pi_ - 2) - xxs0) *
                          b2_spline((double)(pj - 2) - xxs1);
        const double hs = pmod2pi(ns * STEP_D - h);
        const double hd = fabs(pmod2pi(hs - bb * STEP_D + PI_D) - PI_D);
        const double shv = b2_spline(hd / STEP_D);
        coeff[t] = (float)(sx * shv);
    }
    __syncthreads();

    const int c = t >> 4, o = t & 15;
    const float* wc = W + (size_t)c * 3200 + o;  // W[c][m][o], m-stride 16
    float acc = 0.f;
    for (int m = 0; m < 200; ++m) {
        float cm = coeff[m];
        if (cm != 0.f) acc = fmaf(cm, wc[m * 16], acc);
    }
    const int icT = c * 8 + ns;          // k index (0..127)
    const int ocT = n * 16 + o;          // m index (0..127)
    const int kc = icT >> 5, r = icT & 31;
    const int lane = ((r >> 3) << 4) | (ocT & 15);
    const int jj = r & 7;
    const int mf4 = ocT >> 4;
    Af[((((size_t)tap * 4 + kc) * 8 + mf4) * 64 + lane) * 8 + jj] = f2bf(acc);
}

// grid (128, 8) = (y, b); block 256 = 4 waves, each a 64x64 (ocT x x) tile.
__global__ __launch_bounds__(256, 4) void lifted_conv_mfma(
    const float* __restrict__ X, const ushort* __restrict__ Af,
    float* __restrict__ out) {
    // LDS: one input row (all 128 icT) with x-halo, ic-contiguous bf16 pairs.
    // word index = cx*68 + (ihw ^ (((cx>>2)&7)<<2)), ihw = ic/2 in 0..63.
    __shared__ uint xbw[132 * 68];

    const int t = threadIdx.x;
    const int y = blockIdx.x, b = blockIdx.y;
    const int lane = t & 63;
    const int w = t >> 6;
    const int w0 = w >> 1;   // ocT half
    const int w1 = w & 1;    // x half
    const int lrow = lane & 15;
    const int g4 = (lane >> 4) << 2;   // ihw offset from lane

    f32x4 acc[4][4];
#pragma unroll
    for (int a = 0; a < 4; ++a)
#pragma unroll
        for (int q = 0; q < 4; ++q) acc[a][q] = (f32x4){0.f, 0.f, 0.f, 0.f};

    // zero LDS once (halo cols 0,1,130,131 stay zero forever)
#pragma unroll
    for (int it = 0; it < 36; ++it) {
        int idx = t + it * 256;
        if (idx < 132 * 68) xbw[idx] = 0u;
    }

    const float* Xb = X + (size_t)b * (128 * 128 * 128);

    for (int dy = 0; dy < 5; ++dy) {
        const int yy = y + dy - 2;
        if (yy < 0 || yy >= 128) continue;   // block-uniform: contributes zero
        __syncthreads();                      // previous tile reads done
        // ---- stage X row: f32 -> bf16 transpose into LDS ----
#pragma unroll
        for (int it = 0; it < 8; ++it) {
            const int idx = t + it * 256;     // 2048 tasks
            const int ih = idx >> 5;          // ic pair 0..63
            const int g = idx & 31;           // x group
            const int x = g << 2;
            const float* p0 = Xb + ((size_t)(2 * ih) * 128 + yy) * 128 + x;
            const float4 q0 = *(const float4*)p0;
            const float4 q1 = *(const float4*)(p0 + 16384);
            uint pk[4];
            pk[0] = (uint)f2bf(q0.x) | ((uint)f2bf(q1.x) << 16);
            pk[1] = (uint)f2bf(q0.y) | ((uint)f2bf(q1.y) << 16);
            pk[2] = (uint)f2bf(q0.z) | ((uint)f2bf(q1.z) << 16);
            pk[3] = (uint)f2bf(q0.w) | ((uint)f2bf(q1.w) << 16);
#pragma unroll
            for (int q = 0; q < 4; ++q) {
                const int cx = x + 2 + q;
                const int pw = ((cx >> 2) & 7) << 2;
                xbw[cx * 68 + (ih ^ pw)] = pk[q];
            }
        }
        __syncthreads();

        // ---- compute: 5 dx taps, K = 128 ic in 4 chunks of 32 ----
        const int dy5 = dy * 5;
#pragma unroll
        for (int dx = 0; dx < 5; ++dx) {
            const int tap = dy5 + dx;
            const ushort* ap = Af + (size_t)tap * 16384 + (w0 * 4) * 512 + lane * 8;
            const int cx0 = w1 * 64 + lrow + dx;
#pragma unroll
            for (int kc = 0; kc < 4; ++kc) {
                const ushort* apk = ap + kc * 4096;
                short8v av[4];
#pragma unroll
                for (int mf = 0; mf < 4; ++mf)
                    av[mf] = *(const short8v*)(apk + mf * 512);
                short8v bv[4];
                const int ihb = kc * 16 + g4;
#pragma unroll
                for (int nf = 0; nf < 4; ++nf) {
                    const int cx = cx0 + nf * 16;
                    const int pw = ((cx >> 2) & 7) << 2;
                    bv[nf] = *(const short8v*)&xbw[cx * 68 + (ihb ^ pw)];
                }
#pragma unroll
                for (int mf = 0; mf < 4; ++mf)
#pragma unroll
                    for (int nf = 0; nf < 4; ++nf)
                        acc[mf][nf] = __builtin_amdgcn_mfma_f32_16x16x32_bf16(
                            av[mf], bv[nf], acc[mf][nf], 0, 0, 0);
            }
        }
    }

    // ---- epilogue: C/D frag layout col=lane&15, row=(lane>>4)*4+j ----
    const int xcol = w1 * 64 + lrow;
#pragma unroll
    for (int mf = 0; mf < 4; ++mf) {
        const int nn = w0 * 4 + mf;          // ocT>>4
#pragma unroll
        for (int j = 0; j < 4; ++j) {
            const int o = (lane >> 4) * 4 + j;   // ocT&15
            float* op = out + (((size_t)b * 16 + o) * 8 + nn) * 16384 + y * 128 + xcol;
#pragma unroll
            for (int nf = 0; nf < 4; ++nf) op[nf * 16] = acc[mf][nf][j];
        }
    }
}

extern "C" void kernel_launch(void* const* d_in, const int* in_sizes, int n_in,
                              void* d_out, int out_size, void* d_ws, size_t ws_size,
                              hipStream_t stream) {
    const float* X = (const float*)d_in[0];
    const float* W = (const float*)d_in[1];
    float* out = (float*)d_out;
    ushort* Af = (ushort*)d_ws;   // 25*4*8*64*8 bf16 = 819 KB

    build_kst<<<dim3(25, 8, 8), 256, 0, stream>>>(W, Af);
    lifted_conv_mfma<<<dim3(128, 8), 256, 0, stream>>>(X, Af, out);
}

// Round 5
// 244.609 us; speedup vs baseline: 5.6711x; 1.3491x over previous
//
#include <hip/hip_runtime.h>
#include <hip/hip_bf16.h>

// LiftedConv, round 4: bf16 MFMA implicit GEMM with DMA-staged, pre-swizzled X.
//  build_kst : basis x weights -> Af[tap25][kc4][mf8][lane64][8] bf16 (A-frags)
//  xcast     : X f32 (b,ic,y,x) -> Xs bf16-pair planes [b*128+y][2048 chunks],
//              word (cx-2)*64 + (ih ^ ((cx&7)<<2)), ih = ic/2 (halo excluded)
//  lifted_conv_mfma : per (b,y) block, 128 ocT x 128 x, K=3200 via 16x16x32
//              MFMA; rows DMA'd by global_load_lds, double-buffered, vmcnt(8).

#define STEP_F 0.78539816339744831f
#define TWO_PI_F 6.28318530717958648f
#define PI_F 3.14159265358979324f

typedef __attribute__((ext_vector_type(8))) short short8v;
typedef __attribute__((ext_vector_type(4))) float f32x4;

__device__ __forceinline__ float b2f(float x) {
    auto sgn = [](float v) -> float { return (v > 0.f) ? 1.f : ((v < 0.f) ? -1.f : 0.f); };
    float t1 = -3.f * (x - 0.5f) * (x - 0.5f) * sgn(0.5f - x);
    float t2 = (x - 1.5f) * (x - 1.5f) * sgn(1.5f - x);
    float t3 = -3.f * (1.f + 2.f * x) * (1.f + 2.f * x) * sgn(0.5f + x) * 0.25f;
    float t4 = (3.f + 2.f * x) * (3.f + 2.f * x) * sgn(1.5f + x) * 0.25f;
    return (t1 + t2 + t3 + t4) * 0.25f;
}

__device__ __forceinline__ float pmod2pi(float a) {
    float r = fmodf(a, TWO_PI_F);
    if (r < 0.f) r += TWO_PI_F;
    return r;
}

__device__ __forceinline__ ushort f2bf(float f) {
    union { float f; uint u; } v; v.f = f;
    uint u = v.u;
    return (ushort)((u + 0x7FFFu + ((u >> 16) & 1u)) >> 16);  // RNE
}

__device__ __forceinline__ void dma16(const uint* g, uint* l) {
    __builtin_amdgcn_global_load_lds(
        (const __attribute__((address_space(1))) uint*)g,
        (__attribute__((address_space(3))) uint*)l, 16, 0, 0);
}

// ---------------- stage 1: A-fragments ----------------
// grid (25, 8, 8) = (tap, n_samp, n); block 256 = (c=t>>4, o=t&15)
__global__ __launch_bounds__(256) void build_kst(const float* __restrict__ W,
                                                 ushort* __restrict__ Af) {
    __shared__ float coeff[200];
    const int tap = blockIdx.x;
    const int i = tap / 5, j = tap % 5;
    const int ns = blockIdx.y;   // input rotation channel
    const int n  = blockIdx.z;   // output rotation
    const int t = threadIdx.x;

    if (t < 200) {
        const int p = t >> 3, bb = t & 7;
        const int pi_ = p / 5, pj = p % 5;
        const float h = n * STEP_F;
        const float ch = __cosf(h), sh = __sinf(h);
        const float gi = (float)(i - 2), gj = (float)(j - 2);
        const float xxs0 = ch * gi + sh * gj;
        const float xxs1 = -sh * gi + ch * gj;
        const float sx = b2f((float)(pi_ - 2) - xxs0) *
                         b2f((float)(pj - 2) - xxs1);
        const float hs = pmod2pi(ns * STEP_F - h);
        const float hd = fabsf(pmod2pi(hs - bb * STEP_F + PI_F) - PI_F);
        coeff[t] = sx * b2f(hd / STEP_F);
    }
    __syncthreads();

    const int c = t >> 4, o = t & 15;
    const float* wc = W + (size_t)c * 3200 + o;
    float acc = 0.f;
    for (int m = 0; m < 200; ++m) {
        float cm = coeff[m];
        if (cm != 0.f) acc = fmaf(cm, wc[m * 16], acc);  // block-uniform branch
    }
    const int icT = c * 8 + ns;          // k index
    const int ocT = n * 16 + o;          // m index
    const int kc = icT >> 5, r = icT & 31;
    const int lane = ((r >> 3) << 4) | (ocT & 15);
    const int jj = r & 7;
    const int mf4 = ocT >> 4;
    Af[((((size_t)tap * 4 + kc) * 8 + mf4) * 64 + lane) * 8 + jj] = f2bf(acc);
}

// ---------------- stage 2: X pre-cast + transpose + swizzle ----------------
// grid (128, 8) = (y, b); block 256. Plane = 8192 uints = 32 KB.
__global__ __launch_bounds__(256) void xcast(const float* __restrict__ X,
                                             uint* __restrict__ Xs) {
    __shared__ float P[128 * 129];
    const int t = threadIdx.x;
    const int y = blockIdx.x, b = blockIdx.y;
    const float* Xb = X + (size_t)b * (128 * 128 * 128) + y * 128;

    // read 128 ic x 128 x (coalesced 512B runs per ic row)
#pragma unroll
    for (int it = 0; it < 16; ++it) {
        const int f = t + it * 256;          // 0..4095
        const int ic = f >> 5, xg = f & 31;
        const float4 v = *(const float4*)(Xb + (size_t)ic * 16384 + xg * 4);
        float* p = &P[ic * 129 + xg * 4];
        p[0] = v.x; p[1] = v.y; p[2] = v.z; p[3] = v.w;
    }
    __syncthreads();

    // pack to bf16 pairs, pre-swizzled: chunk c -> words 4c..4c+3
    uint* plane = Xs + ((size_t)(b * 128 + y) << 13);
#pragma unroll
    for (int it = 0; it < 8; ++it) {
        const int c = t + it * 256;          // 0..2047
        const int cx = (c >> 4) + 2;         // 2..129
        const int x = cx - 2;
        const int s = (cx & 7) << 2;
        const int ihq0 = (c & 15) * 4;
        uint wv[4];
#pragma unroll
        for (int q = 0; q < 4; ++q) {
            const int ih = (ihq0 + q) ^ s;
            const int ic = 2 * ih;
            wv[q] = (uint)f2bf(P[ic * 129 + x]) |
                    ((uint)f2bf(P[(ic + 1) * 129 + x]) << 16);
        }
        *(uint4*)(plane + (size_t)c * 4) = make_uint4(wv[0], wv[1], wv[2], wv[3]);
    }
}

// ---------------- stage 3: conv ----------------
// grid 1024 (XCD-swizzled to (y,b)); block 256 = 4 waves (2 ocT-half x 2 x-half)
__global__ __launch_bounds__(256, 2) void lifted_conv_mfma(
    const uint* __restrict__ Xs, const ushort* __restrict__ Af,
    float* __restrict__ out) {
    // 2 row buffers of 8448 words (132 cx * 64 ih); epilogue reuse as [128][132] f32
    __shared__ __align__(16) uint sbuf[16896];

    const int t = threadIdx.x;
    const int g = blockIdx.x;
    const int swz = (g & 7) * 128 + (g >> 3);   // XCD x -> image b=x, y-contig
    const int y = swz & 127, b = swz >> 7;
    const int lane = t & 63, w = t >> 6;
    const int w0 = w >> 1, w1 = w & 1;
    const int lrow = lane & 15, g4 = (lane >> 4) << 2;

    // zero halo columns (cx 0,1 -> words 0..127; cx 130,131 -> words 8320..8447)
#pragma unroll
    for (int k = 0; k < 2; ++k) {
        if (t < 128) sbuf[k * 8448 + t] = 0u;
        else         sbuf[k * 8448 + 8320 + (t - 128)] = 0u;
    }

    f32x4 acc[4][4];
#pragma unroll
    for (int a = 0; a < 4; ++a)
#pragma unroll
        for (int q = 0; q < 4; ++q) acc[a][q] = (f32x4){0.f, 0.f, 0.f, 0.f};

    int rlist[5]; int nr = 0;
#pragma unroll
    for (int dy = 0; dy < 5; ++dy) {
        int r = y + dy - 2;
        if (r >= 0 && r < 128) rlist[nr++] = r;
    }

    auto stage = [&](int r, int bufk) {
        const uint* src = Xs + ((size_t)(b * 128 + r) << 13);
#pragma unroll
        for (int i = 0; i < 8; ++i) {
            const int blk = w * 8 + i;                 // 0..31 chunk-blocks
            dma16(src + blk * 256 + lane * 4,
                  &sbuf[bufk * 8448 + 128 + blk * 256]);
        }
    };

    stage(rlist[0], 0);

    for (int idx = 0; idx < nr; ++idx) {
        const bool more = (idx + 1 < nr);
        if (more) stage(rlist[idx + 1], (idx + 1) & 1);
        if (more) __builtin_amdgcn_s_waitcnt(0xF78);   // vmcnt(8): current row done
        else      __builtin_amdgcn_s_waitcnt(0xF70);   // vmcnt(0)
        __syncthreads();

        const int dy = rlist[idx] - y + 2;
        const uint* B = &sbuf[(idx & 1) * 8448];
        const int dy5 = dy * 5;

        __builtin_amdgcn_s_setprio(1);
#pragma unroll
        for (int kc = 0; kc < 4; ++kc) {               // kc outer: 20KB A set, L1-hot
            const int ihb = kc * 16 + g4;
#pragma unroll
            for (int dx = 0; dx < 5; ++dx) {
                const ushort* apk = Af + ((size_t)(dy5 + dx) * 4 + kc) * 4096
                                       + (w0 * 4) * 512 + lane * 8;
                short8v av[4];
#pragma unroll
                for (int mf = 0; mf < 4; ++mf)
                    av[mf] = *(const short8v*)(apk + mf * 512);
                const int cx0 = w1 * 64 + lrow + dx;
                short8v bv[4];
#pragma unroll
                for (int nf = 0; nf < 4; ++nf) {
                    const int cx = cx0 + nf * 16;
                    bv[nf] = *(const short8v*)&B[cx * 64 + (ihb ^ ((cx & 7) << 2))];
                }
#pragma unroll
                for (int mf = 0; mf < 4; ++mf)
#pragma unroll
                    for (int nf = 0; nf < 4; ++nf)
                        acc[mf][nf] = __builtin_amdgcn_mfma_f32_16x16x32_bf16(
                            av[mf], bv[nf], acc[mf][nf], 0, 0, 0);
            }
        }
        __builtin_amdgcn_s_setprio(0);
        __syncthreads();
    }

    // ---- epilogue: regs -> LDS [128][132] f32 -> full-line global stores ----
    float* S = (float*)sbuf;
#pragma unroll
    for (int mf = 0; mf < 4; ++mf) {
#pragma unroll
        for (int j = 0; j < 4; ++j) {
            const int ocT = (w0 * 4 + mf) * 16 + (lane >> 4) * 4 + j;
#pragma unroll
            for (int nf = 0; nf < 4; ++nf) {
                const int x = w1 * 64 + nf * 16 + lrow;
                S[ocT * 132 + x] = acc[mf][nf][j];
            }
        }
    }
    __syncthreads();

    const int l5 = lane >> 5, l31 = lane & 31;
    float* ob = out + (size_t)b * (16 * 8 * 16384) + y * 128;
#pragma unroll
    for (int i = 0; i < 16; ++i) {
        const int row = w * 32 + i * 2 + l5;           // ocT
        const int o = row & 15, n = row >> 4;
        const float4 v = *(const float4*)&S[row * 132 + l31 * 4];
        *(float4*)(ob + ((size_t)o * 8 + n) * 16384 + l31 * 4) = v;
    }
}

extern "C" void kernel_launch(void* const* d_in, const int* in_sizes, int n_in,
                              void* d_out, int out_size, void* d_ws, size_t ws_size,
                              hipStream_t stream) {
    const float* X = (const float*)d_in[0];
    const float* W = (const float*)d_in[1];
    float* out = (float*)d_out;
    ushort* Af = (ushort*)d_ws;                         // 819,200 B
    uint* Xs = (uint*)((char*)d_ws + (1 << 20));        // 33.55 MB (needs ~35 MB ws)

    build_kst<<<dim3(25, 8, 8), 256, 0, stream>>>(W, Af);
    xcast<<<dim3(128, 8), 256, 0, stream>>>(X, Xs);
    lifted_conv_mfma<<<dim3(1024), 256, 0, stream>>>(Xs, Af, out);
}

// Round 8
// 226.427 us; speedup vs baseline: 6.1265x; 1.0803x over previous
//
#include <hip/hip_runtime.h>
#include <hip/hip_bf16.h>

// LiftedConv, round 6: r5 structure + depth-2 software-pipelined K-loop.
//  build_kst : basis x weights -> Af[tap25][kc4][mf8][lane64][8] bf16 (A-frags)
//  xcast     : X f32 (b,ic,y,x) -> Xs bf16-pair planes [b*128+y][2048 chunks],
//              word (cx-2)*64 + (ih ^ ((cx&7)<<2)), ih = ic/2 (halo excluded)
//  lifted_conv_mfma : per (b,y) block, 128 ocT x 128 x, K=3200 via 16x16x32
//              MFMA; rows DMA'd by global_load_lds (vmcnt(8) dbuf); inner
//              (kc,dx) loop rotated depth-2 so L1 A-loads + LDS B-reads
//              overlap MFMA (was serialized: MfmaUtil 38.8%).

#define STEP_F 0.78539816339744831f
#define TWO_PI_F 6.28318530717958648f
#define PI_F 3.14159265358979324f

typedef __attribute__((ext_vector_type(8))) short short8v;
typedef __attribute__((ext_vector_type(4))) float f32x4;

__device__ __forceinline__ float b2f(float x) {
    auto sgn = [](float v) -> float { return (v > 0.f) ? 1.f : ((v < 0.f) ? -1.f : 0.f); };
    float t1 = -3.f * (x - 0.5f) * (x - 0.5f) * sgn(0.5f - x);
    float t2 = (x - 1.5f) * (x - 1.5f) * sgn(1.5f - x);
    float t3 = -3.f * (1.f + 2.f * x) * (1.f + 2.f * x) * sgn(0.5f + x) * 0.25f;
    float t4 = (3.f + 2.f * x) * (3.f + 2.f * x) * sgn(1.5f + x) * 0.25f;
    return (t1 + t2 + t3 + t4) * 0.25f;
}

__device__ __forceinline__ float pmod2pi(float a) {
    float r = fmodf(a, TWO_PI_F);
    if (r < 0.f) r += TWO_PI_F;
    return r;
}

__device__ __forceinline__ ushort f2bf(float f) {
    union { float f; uint u; } v; v.f = f;
    uint u = v.u;
    return (ushort)((u + 0x7FFFu + ((u >> 16) & 1u)) >> 16);  // RNE
}

__device__ __forceinline__ void dma16(const uint* g, uint* l) {
    __builtin_amdgcn_global_load_lds(
        (const __attribute__((address_space(1))) uint*)g,
        (__attribute__((address_space(3))) uint*)l, 16, 0, 0);
}

// ---------------- stage 1: A-fragments ----------------
// grid (25, 8, 8) = (tap, n_samp, n); block 256 = (c=t>>4, o=t&15)
__global__ __launch_bounds__(256) void build_kst(const float* __restrict__ W,
                                                 ushort* __restrict__ Af) {
    __shared__ float coeff[200];
    const int tap = blockIdx.x;
    const int i = tap / 5, j = tap % 5;
    const int ns = blockIdx.y;   // input rotation channel
    const int n  = blockIdx.z;   // output rotation
    const int t = threadIdx.x;

    if (t < 200) {
        const int p = t >> 3, bb = t & 7;
        const int pi_ = p / 5, pj = p % 5;
        const float h = n * STEP_F;
        const float ch = __cosf(h), sh = __sinf(h);
        const float gi = (float)(i - 2), gj = (float)(j - 2);
        const float xxs0 = ch * gi + sh * gj;
        const float xxs1 = -sh * gi + ch * gj;
        const float sx = b2f((float)(pi_ - 2) - xxs0) *
                         b2f((float)(pj - 2) - xxs1);
        const float hs = pmod2pi(ns * STEP_F - h);
        const float hd = fabsf(pmod2pi(hs - bb * STEP_F + PI_F) - PI_F);
        coeff[t] = sx * b2f(hd / STEP_F);
    }
    __syncthreads();

    const int c = t >> 4, o = t & 15;
    const float* wc = W + (size_t)c * 3200 + o;
    float acc = 0.f;
    for (int m = 0; m < 200; ++m) {
        float cm = coeff[m];
        if (cm != 0.f) acc = fmaf(cm, wc[m * 16], acc);  // block-uniform branch
    }
    const int icT = c * 8 + ns;          // k index
    const int ocT = n * 16 + o;          // m index
    const int kc = icT >> 5, r = icT & 31;
    const int lane = ((r >> 3) << 4) | (ocT & 15);
    const int jj = r & 7;
    const int mf4 = ocT >> 4;
    Af[((((size_t)tap * 4 + kc) * 8 + mf4) * 64 + lane) * 8 + jj] = f2bf(acc);
}

// ---------------- stage 2: X pre-cast + transpose + swizzle ----------------
// grid (128, 8) = (y, b); block 256. Plane = 8192 uints = 32 KB.
__global__ __launch_bounds__(256) void xcast(const float* __restrict__ X,
                                             uint* __restrict__ Xs) {
    __shared__ float P[128 * 132];
    const int t = threadIdx.x;
    const int y = blockIdx.x, b = blockIdx.y;
    const float* Xb = X + (size_t)b * (128 * 128 * 128) + y * 128;

    // read 128 ic x 128 x (coalesced 512B runs per ic row), float4 LDS writes
#pragma unroll
    for (int it = 0; it < 16; ++it) {
        const int f = t + it * 256;          // 0..4095
        const int ic = f >> 5, xg = f & 31;
        const float4 v = *(const float4*)(Xb + (size_t)ic * 16384 + xg * 4);
        *(float4*)&P[ic * 132 + xg * 4] = v;
    }
    __syncthreads();

    // pack to bf16 pairs, pre-swizzled: chunk c -> words 4c..4c+3
    uint* plane = Xs + ((size_t)(b * 128 + y) << 13);
#pragma unroll
    for (int it = 0; it < 8; ++it) {
        const int c = t + it * 256;          // 0..2047
        const int cx = (c >> 4) + 2;         // 2..129
        const int x = cx - 2;
        const int s = (cx & 7) << 2;
        const int ihq0 = (c & 15) * 4;
        uint wv[4];
#pragma unroll
        for (int q = 0; q < 4; ++q) {
            const int ih = (ihq0 + q) ^ s;
            const int ic = 2 * ih;
            wv[q] = (uint)f2bf(P[ic * 132 + x]) |
                    ((uint)f2bf(P[(ic + 1) * 132 + x]) << 16);
        }
        *(uint4*)(plane + (size_t)c * 4) = make_uint4(wv[0], wv[1], wv[2], wv[3]);
    }
}

// ---------------- stage 3: conv ----------------
// grid 1024 (XCD-swizzled to (y,b)); block 256 = 4 waves (2 ocT-half x 2 x-half)
__global__ __launch_bounds__(256, 2) void lifted_conv_mfma(
    const uint* __restrict__ Xs, const ushort* __restrict__ Af,
    float* __restrict__ out) {
    // 2 row buffers of 8448 words (132 cx * 64 ih); epilogue reuse as [128][132] f32
    __shared__ __align__(16) uint sbuf[16896];

    const int t = threadIdx.x;
    const int g = blockIdx.x;
    const int swz = (g & 7) * 128 + (g >> 3);   // XCD x -> image b=x, y-contig
    const int y = swz & 127, b = swz >> 7;
    const int lane = t & 63, w = t >> 6;
    const int w0 = w >> 1, w1 = w & 1;
    const int lrow = lane & 15, g4 = (lane >> 4) << 2;

    // zero halo columns (cx 0,1 -> words 0..127; cx 130,131 -> words 8320..8447)
#pragma unroll
    for (int k = 0; k < 2; ++k) {
        if (t < 128) sbuf[k * 8448 + t] = 0u;
        else         sbuf[k * 8448 + 8320 + (t - 128)] = 0u;
    }

    f32x4 acc[4][4];
#pragma unroll
    for (int a = 0; a < 4; ++a)
#pragma unroll
        for (int q = 0; q < 4; ++q) acc[a][q] = (f32x4){0.f, 0.f, 0.f, 0.f};

    int rlist[5]; int nr = 0;
#pragma unroll
    for (int dy = 0; dy < 5; ++dy) {
        int r = y + dy - 2;
        if (r >= 0 && r < 128) rlist[nr++] = r;
    }

    auto stage = [&](int r, int bufk) {
        const uint* src = Xs + ((size_t)(b * 128 + r) << 13);
#pragma unroll
        for (int i = 0; i < 8; ++i) {
            const int blk = w * 8 + i;                 // 0..31 chunk-blocks
            dma16(src + blk * 256 + lane * 4,
                  &sbuf[bufk * 8448 + 128 + blk * 256]);
        }
    };

    stage(rlist[0], 0);

    for (int idx = 0; idx < nr; ++idx) {
        const bool more = (idx + 1 < nr);
        if (more) stage(rlist[idx + 1], (idx + 1) & 1);
        if (more) __builtin_amdgcn_s_waitcnt(0xF78);   // vmcnt(8): current row done
        else      __builtin_amdgcn_s_waitcnt(0xF70);   // vmcnt(0)
        __syncthreads();

        const int dy = rlist[idx] - y + 2;
        const uint* B = &sbuf[(idx & 1) * 8448];
        const int dy5 = dy * 5;
        const ushort* Aw = Af + w0 * 2048 + lane * 8;
        const int cxb = w1 * 64 + lrow;

        // ---- depth-2 rotated pipeline over 20 (kc,dx) iterations ----
        // it issues loads into slot it%3; MFMAs consume slot (it-2)%3.
        short8v avb[3][4], bvb[3][4];
#pragma unroll
        for (int it = 0; it < 22; ++it) {
            if (it < 20) {
                const int kc = it / 5, dx = it % 5;
                const int sl = it % 3;
                const ushort* apk = Aw + ((size_t)(dy5 + dx) * 4 + kc) * 4096;
#pragma unroll
                for (int mf = 0; mf < 4; ++mf)
                    avb[sl][mf] = *(const short8v*)(apk + mf * 512);
                const int ihb = kc * 16 + g4;
                const int cx0 = cxb + dx;
#pragma unroll
                for (int nf = 0; nf < 4; ++nf) {
                    const int cx = cx0 + nf * 16;
                    bvb[sl][nf] = *(const short8v*)&B[cx * 64 + (ihb ^ ((cx & 7) << 2))];
                }
            }
            if (it >= 2) {
                const int sl = (it - 2) % 3;
                __builtin_amdgcn_s_setprio(1);
#pragma unroll
                for (int mf = 0; mf < 4; ++mf)
#pragma unroll
                    for (int nf = 0; nf < 4; ++nf)
                        acc[mf][nf] = __builtin_amdgcn_mfma_f32_16x16x32_bf16(
                            avb[sl][mf], bvb[sl][nf], acc[mf][nf], 0, 0, 0);
                __builtin_amdgcn_s_setprio(0);
            }
        }
        __syncthreads();
    }

    // ---- epilogue: regs -> LDS [128][132] f32 -> full-line global stores ----
    float* S = (float*)sbuf;
#pragma unroll
    for (int mf = 0; mf < 4; ++mf) {
#pragma unroll
        for (int j = 0; j < 4; ++j) {
            const int ocT = (w0 * 4 + mf) * 16 + (lane >> 4) * 4 + j;
#pragma unroll
            for (int nf = 0; nf < 4; ++nf) {
                const int x = w1 * 64 + nf * 16 + lrow;
                S[ocT * 132 + x] = acc[mf][nf][j];
            }
        }
    }
    __syncthreads();

    const int l5 = lane >> 5, l31 = lane & 31;
    float* ob = out + (size_t)b * (16 * 8 * 16384) + y * 128;
#pragma unroll
    for (int i = 0; i < 16; ++i) {
        const int row = w * 32 + i * 2 + l5;           // ocT
        const int o = row & 15, n = row >> 4;
        const float4 v = *(const float4*)&S[row * 132 + l31 * 4];
        *(float4*)(ob + ((size_t)o * 8 + n) * 16384 + l31 * 4) = v;
    }
}

extern "C" void kernel_launch(void* const* d_in, const int* in_sizes, int n_in,
                              void* d_out, int out_size, void* d_ws, size_t ws_size,
                              hipStream_t stream) {
    const float* X = (const float*)d_in[0];
    const float* W = (const float*)d_in[1];
    float* out = (float*)d_out;
    ushort* Af = (ushort*)d_ws;                         // 819,200 B
    uint* Xs = (uint*)((char*)d_ws + (1 << 20));        // 33.55 MB (needs ~35 MB ws)

    build_kst<<<dim3(25, 8, 8), 256, 0, stream>>>(W, Af);
    xcast<<<dim3(128, 8), 256, 0, stream>>>(X, Xs);
    lifted_conv_mfma<<<dim3(1024), 256, 0, stream>>>(Xs, Af, out);
}